// Round 5
// baseline (261.720 us; speedup 1.0000x reference)
//
#include <hip/hip_runtime.h>
#include <math.h>

#define TAU_F 32.0f

typedef __attribute__((ext_vector_type(8))) _Float16 half8;
typedef __attribute__((ext_vector_type(2))) __fp16 half2v;
typedef __attribute__((ext_vector_type(4))) float f32x4;

union HU { uint4 u; half8 v; };

__device__ __forceinline__ void sync_lds_only() {
    // CK-style block_sync_lds: drain LDS ops, leave VMEM (vmcnt) in flight.
    asm volatile("s_waitcnt lgkmcnt(0)" ::: "memory");
    __builtin_amdgcn_s_barrier();
}

// ============ Kernel 1: G partials, fp32 VALU, no atomics (unchanged) ============
// P[ks][192][2048], ks=4. Rows: 0..89 topic, 90..95 zero, 96..185 domain, 186..191 zero.
__global__ __launch_bounds__(256) void gproj2(
    const float* __restrict__ Wt, const float* __restrict__ Wd,
    const float* __restrict__ mem, const int* __restrict__ cat,
    float* __restrict__ P)
{
    __shared__ float Ml[96 * 36];
    __shared__ float Wl[32 * 68];

    const int bid = blockIdx.x;
    const int mat = bid >> 7;
    const int ks  = (bid >> 5) & 3;
    const int ct  = bid & 31;
    const int c0  = ct * 64;
    const int tid = threadIdx.x;
    const float* __restrict__ W = mat ? Wd : Wt;

    const int tr = tid >> 4;
    const int tc = tid & 15;

    float acc[6][4];
    #pragma unroll
    for (int j = 0; j < 6; ++j)
        #pragma unroll
        for (int q = 0; q < 4; ++q) acc[j][q] = 0.f;

    for (int ch = 0; ch < 6; ++ch) {
        __syncthreads();
        #pragma unroll
        for (int p = 0; p < 3; ++p) {
            const int idx = tid + 256 * p;
            const int r   = idx >> 3;
            const int kq  = idx & 7;
            float4 v = make_float4(0.f, 0.f, 0.f, 0.f);
            if (r < 90) {
                const int d = r / 10;
                const int mrow = cat[d] * 10 + (r - d * 10);
                v = *(const float4*)(mem + (size_t)mrow * 768 + ks * 192 + ch * 32 + kq * 4);
            }
            *(float4*)(Ml + r * 36 + kq * 4) = v;
        }
        #pragma unroll
        for (int p = 0; p < 2; ++p) {
            const int idx = tid + 256 * p;
            const int e   = idx >> 4;
            const int c4  = (idx & 15) * 4;
            *(float4*)(Wl + e * 68 + c4) =
                *(const float4*)(W + (size_t)(ks * 192 + ch * 32 + e) * 2048 + c0 + c4);
        }
        __syncthreads();

        #pragma unroll
        for (int e = 0; e < 32; e += 4) {
            float4 m4[6], w4[4];
            #pragma unroll
            for (int j = 0; j < 6; ++j) m4[j] = *(const float4*)(Ml + (tr * 6 + j) * 36 + e);
            #pragma unroll
            for (int q = 0; q < 4; ++q) w4[q] = *(const float4*)(Wl + (e + q) * 68 + tc * 4);
            #pragma unroll
            for (int j = 0; j < 6; ++j) {
                const float mv[4] = {m4[j].x, m4[j].y, m4[j].z, m4[j].w};
                #pragma unroll
                for (int q = 0; q < 4; ++q) {
                    acc[j][0] = fmaf(mv[q], w4[q].x, acc[j][0]);
                    acc[j][1] = fmaf(mv[q], w4[q].y, acc[j][1]);
                    acc[j][2] = fmaf(mv[q], w4[q].z, acc[j][2]);
                    acc[j][3] = fmaf(mv[q], w4[q].w, acc[j][3]);
                }
            }
        }
    }

    #pragma unroll
    for (int j = 0; j < 6; ++j) {
        float4 v = make_float4(acc[j][0], acc[j][1], acc[j][2], acc[j][3]);
        *(float4*)(P + (size_t)ks * 393216 + (size_t)(mat * 96 + tr * 6 + j) * 2048 + c0 + tc * 4) = v;
    }
}

// ============ Kernel 2: reduce partials -> f16 hi/lo, fragment-major (unchanged) ============
// col-frag cf = nq*3+j in 0..11 (0..5 topic, 6..11 domain);
// addr (halves) = ((kc*12 + cf)*2 + plane)*512 + lq*128 + lm*8
__global__ __launch_bounds__(256) void split_g3(
    const float* __restrict__ P, unsigned short* __restrict__ gB)
{
    const int u  = blockIdx.x * 256 + threadIdx.x;  // 0..49151
    const int n  = u >> 8;                          // 0..191
    const int k0 = (u & 255) * 8;                   // 0..2040

    float s[8] = {0.f, 0.f, 0.f, 0.f, 0.f, 0.f, 0.f, 0.f};
    #pragma unroll
    for (int ks = 0; ks < 4; ++ks) {
        const float4 a = *(const float4*)(P + (size_t)ks * 393216 + (size_t)n * 2048 + k0);
        const float4 b = *(const float4*)(P + (size_t)ks * 393216 + (size_t)n * 2048 + k0 + 4);
        s[0] += a.x; s[1] += a.y; s[2] += a.z; s[3] += a.w;
        s[4] += b.x; s[5] += b.y; s[6] += b.z; s[7] += b.w;
    }
    union { _Float16 h[8]; uint4 u4; } hi, lo;
    #pragma unroll
    for (int e = 0; e < 8; ++e) {
        const _Float16 h = (_Float16)s[e];   // RNE
        hi.h[e] = h;
        lo.h[e] = (_Float16)(s[e] - (float)h);
    }
    const int kc = k0 >> 5;
    const int lq = (k0 >> 3) & 3;
    const int nq = n / 48;
    const int rm = n - nq * 48;
    const int j  = rm >> 4;
    const int lm = rm & 15;
    const size_t fH = (size_t)((kc * 12 + nq * 3 + j) * 2 + 0) * 512 + lq * 128 + lm * 8;
    const size_t fL = (size_t)((kc * 12 + nq * 3 + j) * 2 + 1) * 512 + lq * 128 + lm * 8;
    *(uint4*)(gB + fH) = hi.u4;
    *(uint4*)(gB + fL) = lo.u4;
}

// ============ Kernel 3: M=64 full-K split-f16 MFMA GEMM + fused softmax epilogue ======
// 256 blocks (1/CU) x 512 thr (8 waves), 64 rows/block, full K=2048, 32 iters of K=64.
// B (gB fragments) staged global->reg->LDS one iter ahead, SHARED by both 32-row halves:
// per-CU B L2 traffic halves vs the 512-block version (72->36 KB/iter) and B's L2
// latency leaves the critical path (ds_write's auto vmcnt wait lands ~1 iter after issue).
// Wave roles: iw = w>>2 selects row half (i-blocks {0,1} or {2,3}); r = w&3 as before:
//   r<2 : topic frags {2r,2r+1}, 3 split-passes -> 24 MFMA/iter
//   r>=2: topic frag {2+r} (3 passes) + domain frags {6+3(r-2)..+2} (1 pass) -> 24 MFMA/iter
// Per-acc accumulation order identical to R4 kernel => bit-identical output.
__global__ __launch_bounds__(512, 2) void fused_ep(
    const float* __restrict__ feat, const unsigned short* __restrict__ gB,
    float* __restrict__ out)
{
    // LDS carve (114,688 B total):
    //   aS: [buf2][plane2][kf2][row64][40] halves = 40,960 B  (A staging, dbuf)
    //   Bl: [buf2][36 planes][512] halves        = 73,728 B  (B staging, dbuf)
    //   sc: [row64][193] floats = 49,408 B  (REUSES the aS+Bl region after the loop)
    __shared__ __align__(16) unsigned char smraw[114688];
    unsigned short* aS = (unsigned short*)smraw;
    unsigned short* Bl = (unsigned short*)(smraw + 40960);
    float* sc = (float*)smraw;
    __shared__ float ssqS[64];

    const int tid  = threadIdx.x;
    const int row0 = blockIdx.x * 64;

    const int w  = tid >> 6, l = tid & 63;
    const int lm = l & 15,  lq = l >> 4;
    const int iw = w >> 2;              // row half: i-blocks {2iw, 2iw+1}
    const int r  = w & 3;               // fragment role
    const bool roleT = (r < 2);
    const int f0 = 4 * r;               // roleT planes f0..f0+3 (cf 2r h/l, 2r+1 h/l)
    const int tf = 2 + r;               // roleM topic frag (4 or 5)
    const int tp = 2 * tf;              // roleM topic planes tp, tp+1
    const int dp = 12 + 3 * (r - 2);    // roleM domain planes dp..dp+2
    const int db = 6 + 3 * (r - 2);     // roleM domain col-frags
    const int sr = tid >> 3, kq = tid & 7;   // A staging: row 0..63, k-octet 0..7
    const int skf = kq >> 2, sk4 = kq & 3;

    f32x4 acc[2][4];
    #pragma unroll
    for (int i = 0; i < 2; ++i)
        #pragma unroll
        for (int j = 0; j < 4; ++j) acc[i][j] = (f32x4)0.f;
    float ssq = 0.f;

    const float* fbase = feat + (size_t)(row0 + sr) * 2048 + kq * 8;

    // ---- B stage plane assignment: wave w stages planes p = w, w+8, ..., p<36 ----
    // plane fi (within a kf half): 0..11 = topic cf*2+pl, 12..17 = domain (cf-6), h only
    auto loadB = [&](int kt2, uint4* bn) {
        #pragma unroll
        for (int s = 0; s < 5; ++s) {
            const int p = w + 8 * s;
            if (p < 36) {
                const int kf = (p >= 18) ? 1 : 0;
                const int fi = p - kf * 18;
                const int cf = (fi < 12) ? (fi >> 1) : (fi - 6);
                const int pl = (fi < 12) ? (fi & 1) : 0;
                bn[s] = *(const uint4*)(gB + (size_t)(((2 * kt2 + kf) * 12 + cf) * 1024)
                                           + pl * 512 + l * 8);
            }
        }
    };
    auto writeB = [&](int buf, const uint4* bn) {
        #pragma unroll
        for (int s = 0; s < 5; ++s) {
            const int p = w + 8 * s;
            if (p < 36)
                *(uint4*)(Bl + ((size_t)buf * 36 + p) * 512 + l * 8) = bn[s];
        }
    };

    // convert+stage A helper (fp32 -> f16 hi/lo planes, fused ssq)
    auto cw = [&](int buf, float4 va, float4 vb) {
        const float xs[8] = {va.x, va.y, va.z, va.w, vb.x, vb.y, vb.z, vb.w};
        union { half2v h2[4]; uint4 u4; } uh, ul;
        #pragma unroll
        for (int e = 0; e < 4; ++e) {
            const float a = xs[2 * e], b = xs[2 * e + 1];
            ssq = fmaf(a, a, ssq); ssq = fmaf(b, b, ssq);
            half2v h = __builtin_amdgcn_cvt_pkrtz(a, b);
            uh.h2[e] = h;
            ul.h2[e] = __builtin_amdgcn_cvt_pkrtz(a - (float)h[0], b - (float)h[1]);
        }
        *(uint4*)(aS + (size_t)(((buf * 2 + 0) * 2 + skf) * 64 + sr) * 40 + sk4 * 8) = uh.u4;
        *(uint4*)(aS + (size_t)(((buf * 2 + 1) * 2 + skf) * 64 + sr) * 40 + sk4 * 8) = ul.u4;
    };

    // ---- prologue: B(0) -> Bl buf0; A steps 0,1 -> regs; stage A step 0 ----
    {
        uint4 b0[5];
        loadB(0, b0);
        float4 c0a = *(const float4*)(fbase);
        float4 c0b = *(const float4*)(fbase + 4);
        cw(0, c0a, c0b);
        writeB(0, b0);   // compiler inserts vmcnt wait for b0 here
    }
    float4 c1a = *(const float4*)(fbase + 64);
    float4 c1b = *(const float4*)(fbase + 68);
    sync_lds_only();

    for (int kt = 0; kt < 32; ++kt) {
        const int cb = kt & 1;
        // 1. issue B loads for kt+1 (land in regs; written to LDS after MFMA)
        uint4 bn[5];
        if (kt < 31) loadB(kt + 1, bn);
        // 2. A prefetch for kt+2 (rides through barrier; never drained)
        const int ka = (kt + 2 < 32) ? kt + 2 : 31;
        float4 cna = *(const float4*)(fbase + ka * 64);
        float4 cnb = *(const float4*)(fbase + ka * 64 + 4);
        // 3. stage A step kt+1 into other buffer
        if (kt < 31) cw((kt + 1) & 1, c1a, c1b);

        // 4. A fragments from aS[cb] for this wave's row half
        half8 fh[2][2], fl[2][2];
        #pragma unroll
        for (int ii = 0; ii < 2; ++ii)
            #pragma unroll
            for (int kf = 0; kf < 2; ++kf) {
                const int row = (iw * 2 + ii) * 16 + lm;
                HU th, tl;
                th.u = *(const uint4*)(aS + (size_t)(((cb * 2 + 0) * 2 + kf) * 64 + row) * 40 + lq * 8);
                tl.u = *(const uint4*)(aS + (size_t)(((cb * 2 + 1) * 2 + kf) * 64 + row) * 40 + lq * 8);
                fh[ii][kf] = th.v;
                fl[ii][kf] = tl.v;
            }

        // 5. B fragments from Bl[cb] + MFMA (order identical to R4)
        if (roleT) {
            #pragma unroll
            for (int kf = 0; kf < 2; ++kf) {
                const unsigned short* bp = Bl + ((size_t)cb * 36 + kf * 18) * 512 + l * 8;
                HU hA, hB, hC, hD;
                hA.u = *(const uint4*)(bp + (size_t)(f0 + 0) * 512);
                hB.u = *(const uint4*)(bp + (size_t)(f0 + 1) * 512);
                hC.u = *(const uint4*)(bp + (size_t)(f0 + 2) * 512);
                hD.u = *(const uint4*)(bp + (size_t)(f0 + 3) * 512);
                #pragma unroll
                for (int ii = 0; ii < 2; ++ii) {
                    acc[ii][0] = __builtin_amdgcn_mfma_f32_16x16x32_f16(fh[ii][kf], hA.v, acc[ii][0], 0, 0, 0);
                    acc[ii][0] = __builtin_amdgcn_mfma_f32_16x16x32_f16(fh[ii][kf], hB.v, acc[ii][0], 0, 0, 0);
                    acc[ii][0] = __builtin_amdgcn_mfma_f32_16x16x32_f16(fl[ii][kf], hA.v, acc[ii][0], 0, 0, 0);
                    acc[ii][1] = __builtin_amdgcn_mfma_f32_16x16x32_f16(fh[ii][kf], hC.v, acc[ii][1], 0, 0, 0);
                    acc[ii][1] = __builtin_amdgcn_mfma_f32_16x16x32_f16(fh[ii][kf], hD.v, acc[ii][1], 0, 0, 0);
                    acc[ii][1] = __builtin_amdgcn_mfma_f32_16x16x32_f16(fl[ii][kf], hC.v, acc[ii][1], 0, 0, 0);
                }
            }
        } else {
            #pragma unroll
            for (int kf = 0; kf < 2; ++kf) {
                const unsigned short* bp = Bl + ((size_t)cb * 36 + kf * 18) * 512 + l * 8;
                HU hA, hB, hC, hD, hE;
                hA.u = *(const uint4*)(bp + (size_t)(tp + 0) * 512);
                hB.u = *(const uint4*)(bp + (size_t)(tp + 1) * 512);
                hC.u = *(const uint4*)(bp + (size_t)(dp + 0) * 512);
                hD.u = *(const uint4*)(bp + (size_t)(dp + 1) * 512);
                hE.u = *(const uint4*)(bp + (size_t)(dp + 2) * 512);
                #pragma unroll
                for (int ii = 0; ii < 2; ++ii) {
                    acc[ii][0] = __builtin_amdgcn_mfma_f32_16x16x32_f16(fh[ii][kf], hA.v, acc[ii][0], 0, 0, 0);
                    acc[ii][0] = __builtin_amdgcn_mfma_f32_16x16x32_f16(fh[ii][kf], hB.v, acc[ii][0], 0, 0, 0);
                    acc[ii][0] = __builtin_amdgcn_mfma_f32_16x16x32_f16(fl[ii][kf], hA.v, acc[ii][0], 0, 0, 0);
                    acc[ii][1] = __builtin_amdgcn_mfma_f32_16x16x32_f16(fh[ii][kf], hC.v, acc[ii][1], 0, 0, 0);
                    acc[ii][2] = __builtin_amdgcn_mfma_f32_16x16x32_f16(fh[ii][kf], hD.v, acc[ii][2], 0, 0, 0);
                    acc[ii][3] = __builtin_amdgcn_mfma_f32_16x16x32_f16(fh[ii][kf], hE.v, acc[ii][3], 0, 0, 0);
                }
            }
        }

        // 6. B(kt+1) regs -> Bl other buffer (vmcnt auto-wait; ~1 iter after issue)
        if (kt < 31) writeB((kt + 1) & 1, bn);

        sync_lds_only();   // lgkm drain + barrier only — A-prefetch vmcnt rides through
        c1a = cna; c1b = cnb;
    }

    // ---- scores -> LDS (overwrites staging region; safe after final barrier) ----
    if (roleT) {
        #pragma unroll
        for (int ii = 0; ii < 2; ++ii)
            #pragma unroll
            for (int f = 0; f < 2; ++f)
                #pragma unroll
                for (int r4 = 0; r4 < 4; ++r4)
                    sc[((iw * 2 + ii) * 16 + lq * 4 + r4) * 193 + (2 * r + f) * 16 + lm] = acc[ii][f][r4];
    } else {
        #pragma unroll
        for (int ii = 0; ii < 2; ++ii)
            #pragma unroll
            for (int f = 0; f < 4; ++f) {
                const int cf = (f == 0) ? tf : (db + f - 1);
                #pragma unroll
                for (int r4 = 0; r4 < 4; ++r4)
                    sc[((iw * 2 + ii) * 16 + lq * 4 + r4) * 193 + cf * 16 + lm] = acc[ii][f][r4];
            }
    }

    // ssq: 8 staging threads per row (kq 0..7) -> full-row |feat|^2
    ssq += __shfl_xor(ssq, 1, 64);
    ssq += __shfl_xor(ssq, 2, 64);
    ssq += __shfl_xor(ssq, 4, 64);
    if (kq == 0) ssqS[sr] = ssq;
    __syncthreads();

    // ---- softmax epilogue: 2 lanes per row (domains 0..4 / 5..8), waves 0-1 ----
    if (tid < 128) {
        const int rr = tid >> 1, hf = tid & 1;
        const int nd = hf ? 4 : 5;
        const int d0 = hf ? 5 : 0;
        const float inv = TAU_F / fmaxf(sqrtf(ssqS[rr]), 1e-12f);
        const float* scr = sc + (size_t)rr * 193;
        float lg[5];
        float dmax = -1e30f;
        #pragma unroll
        for (int dd = 0; dd < 5; ++dd) {
            if (dd < nd) {
                const int d = d0 + dd;
                const float* v = scr + d * 10;          // topic cols 0..89
                const float* u = scr + 96 + d * 10;     // domain cols 96..185
                float mx = v[0];
                #pragma unroll
                for (int m = 1; m < 10; ++m) mx = fmaxf(mx, v[m]);
                float ssum = 0.f, dot = 0.f;
                #pragma unroll
                for (int m = 0; m < 10; ++m) {
                    const float p = __expf((v[m] - mx) * inv);
                    ssum += p;
                    dot = fmaf(p, u[m], dot);
                }
                const float lgt = (dot / ssum) * inv;
                lg[dd] = lgt;
                dmax = fmaxf(dmax, lgt);
            } else {
                lg[dd] = -1e30f;                        // exp -> 0, doesn't affect sums
            }
        }
        dmax = fmaxf(dmax, __shfl_xor(dmax, 1, 64));
        float s2 = 0.f;
        #pragma unroll
        for (int dd = 0; dd < 5; ++dd) {
            const float p = __expf(lg[dd] - dmax);
            lg[dd] = p;
            s2 += p;
        }
        s2 += __shfl_xor(s2, 1, 64);
        const float r2 = 1.0f / s2;
        #pragma unroll
        for (int dd = 0; dd < 5; ++dd)
            if (dd < nd)
                out[(size_t)(row0 + rr) * 9 + d0 + dd] = lg[dd] * r2;
    }
}

extern "C" void kernel_launch(void* const* d_in, const int* in_sizes, int n_in,
                              void* d_out, int out_size, void* d_ws, size_t ws_size,
                              hipStream_t stream) {
    const float* feature = (const float*)d_in[0];
    const float* Wt      = (const float*)d_in[1];
    const float* Wd      = (const float*)d_in[2];
    const float* mem     = (const float*)d_in[3];
    const int*   cat     = (const int*)d_in[4];

    // ws layout: P (6.3 MB) | gB 1.57 MB @50331648
    float* P  = (float*)d_ws;
    unsigned short* gB = (unsigned short*)((char*)d_ws + 50331648);
    float* out = (float*)d_out;

    gproj2<<<256, 256, 0, stream>>>(Wt, Wd, mem, cat, P);
    split_g3<<<192, 256, 0, stream>>>(P, gB);
    fused_ep<<<256, 512, 0, stream>>>(feature, gB, out);
}